// Round 7
// baseline (979.952 us; speedup 1.0000x reference)
//
#include <hip/hip_runtime.h>

#define T_STEPS 1024
#define BATCH 2048
#define PS 36   // plane row stride in u32 words; 36%32==4 spreads nb across banks; 144B is 16B-aligned

typedef short short8 __attribute__((ext_vector_type(8)));
typedef float f32x4 __attribute__((ext_vector_type(4)));
typedef float f32x2 __attribute__((ext_vector_type(2)));

__device__ __forceinline__ float fast_rcp(float x) {
#if __has_builtin(__builtin_amdgcn_rcpf)
    return __builtin_amdgcn_rcpf(x);
#else
    return 1.0f / x;
#endif
}
__device__ __forceinline__ float fast_exp2(float x) {
#if __has_builtin(__builtin_amdgcn_exp2f)
    return __builtin_amdgcn_exp2f(x);
#else
    return exp2f(x);
#endif
}
__device__ __forceinline__ float sigf(float x) {
    return fast_rcp(1.0f + fast_exp2(-1.44269504f * x));
}
__device__ __forceinline__ f32x2 sigf2(f32x2 v) {
    f32x2 t = v * (-1.44269504f);
    f32x2 e = {fast_exp2(t[0]), fast_exp2(t[1])};
    e = e + 1.0f;
    return f32x2{fast_rcp(e[0]), fast_rcp(e[1])};
}
__device__ __forceinline__ float tanh_fast(float x) {
    float e = fast_exp2(2.88539008f * x);
    return 1.0f - 2.0f * fast_rcp(e + 1.0f);
}
__device__ __forceinline__ unsigned f2bf(float x) {
    unsigned u = __float_as_uint(x);
    unsigned r = u + 0x7FFFu + ((u >> 16) & 1u);
    return r >> 16;
}
__device__ __forceinline__ float bf2f(unsigned b) {
    return __uint_as_float(b << 16);
}
__device__ __forceinline__ unsigned cvt_pk_bf16(float a, float b) {
    unsigned r;
    asm("v_cvt_pk_bf16_f32 %0, %1, %2" : "=v"(r) : "v"(a), "v"(b));
    return r;
}

// DPP conventions (HW-validated R2-R7 + v8's working sel4A): 0x110+N = row_shr N
// (lane l <- lane l-N within 16-lane row); bank_mask selects 4-lane banks to
// update; bound_ctrl=false: out-of-row source lanes KEEP OLD dst.
//
// Merged gather: cell (nb=c&1, uh=c>>1) at lane pos 4r+c needs the C-tile value
// from source pos nb.  uh=0 lanes (pos 4r..4r+1): shift 4r from tile A.
// uh=1 lanes (pos 4r+2..4r+3): shift 4r+2 from tile C.  The C-chain's invalid
// source lanes (pos 4r,4r+1) preserve the A-chain values -> one register.
__device__ __forceinline__ float sel_merge(f32x4 A, f32x4 C) {
    int v = __float_as_int(A[0]);                                        // pos 0,1 (bank0, shift 0)
    v = __builtin_amdgcn_update_dpp(v, __float_as_int(A[1]), 0x114, 0xf, 0x2, false);
    v = __builtin_amdgcn_update_dpp(v, __float_as_int(A[2]), 0x118, 0xf, 0x4, false);
    v = __builtin_amdgcn_update_dpp(v, __float_as_int(A[3]), 0x11C, 0xf, 0x8, false);
    v = __builtin_amdgcn_update_dpp(v, __float_as_int(C[0]), 0x112, 0xf, 0x1, false);
    v = __builtin_amdgcn_update_dpp(v, __float_as_int(C[1]), 0x116, 0xf, 0x2, false);
    v = __builtin_amdgcn_update_dpp(v, __float_as_int(C[2]), 0x11A, 0xf, 0x4, false);
    v = __builtin_amdgcn_update_dpp(v, __float_as_int(C[3]), 0x11E, 0xf, 0x8, false);
    return __int_as_float(v);
}
__device__ __forceinline__ float dpp_shl4f(float v) {
    return __int_as_float(__builtin_amdgcn_update_dpp(0, __float_as_int(v), 0x104, 0xf, 0xf, true));
}

// Layer-2 cell for 2 batches, fully in-wave.  Reads c-plane fragments from the
// given (read) buffer, computes gates via hi/lo-split MFMAs (v8's term set),
// stores out and updates register state (lanes 0-1 carry batch l's h1/c1).
__device__ __forceinline__ void l2_step(const unsigned* br, int fro,
                                        const short8* a2h, const short8* a2l,
                                        const float* whh1v, const float* b1v,
                                        float& h1r, float& c1r,
                                        int l, float* __restrict__ out,
                                        int bb, int tout)
{
    const unsigned* Ch = br + 2 * PS;   // plane 1 (c hi)
    const unsigned* Cl = br + 4 * PS;   // plane 2 (c lo)
    short8 ch0 = *reinterpret_cast<const short8*>(Ch + fro);
    short8 ch1 = *reinterpret_cast<const short8*>(Ch + fro + 16);
    short8 cl0 = *reinterpret_cast<const short8*>(Cl + fro);
    short8 cl1 = *reinterpret_cast<const short8*>(Cl + fro + 16);
    f32x4 zA = {0.0f, 0.0f, 0.0f, 0.0f};
    f32x4 zB = {0.0f, 0.0f, 0.0f, 0.0f};
    zA = __builtin_amdgcn_mfma_f32_16x16x32_bf16(a2h[0], ch0, zA, 0, 0, 0);
    zB = __builtin_amdgcn_mfma_f32_16x16x32_bf16(a2l[1], ch1, zB, 0, 0, 0);
    zA = __builtin_amdgcn_mfma_f32_16x16x32_bf16(a2h[1], ch1, zA, 0, 0, 0);
    zB = __builtin_amdgcn_mfma_f32_16x16x32_bf16(a2h[0], cl0, zB, 0, 0, 0);
    zA = __builtin_amdgcn_mfma_f32_16x16x32_bf16(a2l[0], ch0, zA, 0, 0, 0);
    zB = __builtin_amdgcn_mfma_f32_16x16x32_bf16(a2h[1], cl1, zB, 0, 0, 0);
    f32x4 z = zA + zB;
    float g1i = z[0] + b1v[0] + h1r * whh1v[0];
    float g1f = z[1] + b1v[1] + h1r * whh1v[1];
    float g1g = z[2] + b1v[2] + h1r * whh1v[2];
    float g1o = z[3] + b1v[3] + h1r * whh1v[3];
    float c1n = sigf(g1f) * c1r + sigf(g1i) * tanh_fast(g1g);
    float h1n = sigf(g1o) * tanh_fast(c1n);
    if (l < 2)
        out[(size_t)(bb + l) * T_STEPS + tout] = c1n;
    h1r = h1n;   // only lanes 0-1 meaningful; others bounded garbage
    c1r = c1n;
}

// v15: barrier-free.  Each wave is a self-contained 2-batch LSTM: it holds all
// of W_hh0 in registers (a1[16][2], 128 VGPR), computes all 256 gate rows
// (32 MFMAs), gathers gates in-register (sel_merge), runs both layers, and
// exchanges h/c with ITSELF via a private LDS plane roundtrip (in-order per
// wave -> no sync of any kind).  Block = 4 independent waves (no barriers);
// grid 256 -> 1 block/CU, 1 wave/SIMD, 1024 waves total.  Removes the per-step
// barrier skew + entrainment that bounded v8-v14 at ~1366 cyc/step.
__global__ __launch_bounds__(256, 1)
void lstm_v15_kernel(const float* __restrict__ input,
                     const float* __restrict__ W_ih0,
                     const float* __restrict__ W_hh0,
                     const float* __restrict__ b_ih0,
                     const float* __restrict__ b_hh0,
                     const float* __restrict__ W_ih1,
                     const float* __restrict__ W_hh1,
                     const float* __restrict__ b_ih1,
                     const float* __restrict__ b_hh1,
                     float* __restrict__ out)
{
    const int tid = threadIdx.x;
    const int w   = tid >> 6;
    const int l   = tid & 63;
    const int q16 = l >> 4;
    const int n16 = l & 15;
    const int c   = l & 3;          // encodes (nb, uh)
    const int nb  = c & 1;          // batch within wave (0/1)
    const int uh  = c >> 1;
    const int r   = (l >> 2) & 3;
    const int rh  = (l >> 3) & 1;   // r>>1
    const int bb  = blockIdx.x * 8 + w * 2;

    // per-wave private LDS: planes [par][plane(h,chi,clo)][nb][PS] + X buffer
    __shared__ __align__(16) unsigned HP[4][2][3][2][PS];   // 6.9 KB
    __shared__ float Xb[4][2][2][65];                       // 4.2 KB

    for (int i = l; i < 2 * 3 * 2 * PS; i += 64)
        reinterpret_cast<unsigned*>(HP[w])[i] = 0u;

    // ---- W_hh0 fragments: a1[rt][kt], tile rt = rows 16rt..16rt+15 ----
    short8 a1[16][2];
    #pragma unroll
    for (int rt = 0; rt < 16; ++rt) {
        #pragma unroll
        for (int kt = 0; kt < 2; ++kt) {
            const float* p = W_hh0 + (size_t)(16 * rt + n16) * 64 + kt * 32 + q16 * 8;
            short8 a;
            #pragma unroll
            for (int j = 0; j < 8; ++j) a[j] = (short)f2bf(p[j]);
            a1[rt][kt] = a;
        }
    }
    // ---- L2 A-fragments (hi/lo split), rows m>=4 zero ----
    short8 a2h[2], a2l[2];
    #pragma unroll
    for (int kt = 0; kt < 2; ++kt) {
        short8 ah = {0,0,0,0,0,0,0,0}, al = {0,0,0,0,0,0,0,0};
        if (n16 < 4) {
            const float* p = W_ih1 + (size_t)n16 * 64 + kt * 32 + q16 * 8;
            #pragma unroll
            for (int j = 0; j < 8; ++j) {
                unsigned hb = f2bf(p[j]);
                ah[j] = (short)hb;
                al[j] = (short)f2bf(p[j] - bf2f(hb));
            }
        }
        a2h[kt] = ah; a2l[kt] = al;
    }

    // ---- activation constants for the lane's two cells (jj = 0,1) ----
    f32x2 w01[2], w23[2], b01[2], b23[2];
    #pragma unroll
    for (int jj = 0; jj < 2; ++jj) {
        const int u = 32 * jj + 16 * uh + 4 * q16 + r;
        float wgv[4], bgv[4];
        #pragma unroll
        for (int gg = 0; gg < 4; ++gg) {
            int row = gg * 64 + u;
            wgv[gg] = W_ih0[row];
            bgv[gg] = b_ih0[row] + b_hh0[row];
        }
        w01[jj] = f32x2{wgv[0], wgv[1]}; w23[jj] = f32x2{wgv[2], wgv[3]};
        b01[jj] = f32x2{bgv[0], bgv[1]}; b23[jj] = f32x2{bgv[2], bgv[3]};
    }
    float whh1v[4], b1v[4];
    #pragma unroll
    for (int g = 0; g < 4; ++g) { whh1v[g] = W_hh1[g]; b1v[g] = b_ih1[g] + b_hh1[g]; }

    const float* inrowA = input + (size_t)bb * T_STEPS;
    const float* inrowB = inrowA + T_STEPS;
    Xb[w][0][0][l] = inrowA[l];
    Xb[w][0][1][l] = inrowB[l];
    float xnA = 0.0f, xnB = 0.0f;
    float c0s[2] = {0.0f, 0.0f};
    float h1r = 0.0f, c1r = 0.0f;

    const int fro = nb * PS + 4 * q16;   // fragment read offset within a plane
    int par = 0;

    for (int t = 0; t < T_STEPS; ++t) {
        if ((t & 63) == 0 && t + 64 < T_STEPS) {
            xnA = inrowA[t + 64 + l];
            xnB = inrowB[t + 64 + l];
        }
        const int cp = (t >> 6) & 1;

        const unsigned* br = &HP[w][par][0][0][0];
        unsigned*       bw = &HP[w][par ^ 1][0][0][0];

        // ---- B-fragments: h(t-1) (intra-wave, in-order after last step's writes) ----
        short8 hb0 = *reinterpret_cast<const short8*>(br + fro);
        short8 hb1 = *reinterpret_cast<const short8*>(br + fro + 16);

        // ---- L1 MFMA: all 16 row-tiles ----
        f32x4 acc[16];
        #pragma unroll
        for (int rt = 0; rt < 16; ++rt) {
            f32x4 z = {0.0f, 0.0f, 0.0f, 0.0f};
            z = __builtin_amdgcn_mfma_f32_16x16x32_bf16(a1[rt][0], hb0, z, 0, 0, 0);
            z = __builtin_amdgcn_mfma_f32_16x16x32_bf16(a1[rt][1], hb1, z, 0, 0, 0);
            acc[rt] = z;
        }

        // ---- layer-2 for step t-1 (pipelined; c-planes of t-1 are in br) ----
        if (t > 0)
            l2_step(br, fro, a2h, a2l, whh1v, b1v, h1r, c1r, l, out, bb, t - 1);

        // ---- in-register gate gather: tiles 4g+2jj+{0,1} -> one value/lane ----
        float g4[2][4];
        #pragma unroll
        for (int jj = 0; jj < 2; ++jj)
            #pragma unroll
            for (int gg = 0; gg < 4; ++gg)
                g4[jj][gg] = sel_merge(acc[4 * gg + 2 * jj], acc[4 * gg + 2 * jj + 1]);

        // ---- layer-1 activation + pack for both cells ----
        float x = Xb[w][cp][nb][t & 63];
        f32x2 xx = {x, x};
        #pragma unroll
        for (int jj = 0; jj < 2; ++jj) {
            f32x2 gif = f32x2{g4[jj][0], g4[jj][1]} + (xx * w01[jj] + b01[jj]);
            f32x2 ggo = f32x2{g4[jj][2], g4[jj][3]} + (xx * w23[jj] + b23[jj]);
            f32x2 sif = sigf2(gif);
            float tg  = tanh_fast(ggo[0]);
            float c0n = sif[1] * c0s[jj] + sif[0] * tg;
            c0s[jj] = c0n;
            float h0n = sigf(ggo[1]) * tanh_fast(c0n);

            float ph = dpp_shl4f(h0n);           // partner unit u+1 (lane l+4)
            float pc = dpp_shl4f(c0n);
            unsigned hword  = cvt_pk_bf16(h0n, ph);
            unsigned chword = cvt_pk_bf16(c0n, pc);
            float hi_own = bf2f(chword & 0xFFFFu);
            float lo_own = c0n - hi_own;
            float plo = dpp_shl4f(lo_own);
            unsigned clword = cvt_pk_bf16(lo_own, plo);
            if (!(l & 4)) {                      // r even: owns pair (u, u+1)
                int widx = nb * PS + 16 * jj + 8 * uh + 2 * q16 + rh;
                bw[widx]          = hword;
                bw[2 * PS + widx] = chword;
                bw[4 * PS + widx] = clword;
            }
        }

        if ((t & 63) == 63 && t + 1 < T_STEPS) {
            Xb[w][cp ^ 1][0][l] = xnA;
            Xb[w][cp ^ 1][1][l] = xnB;
        }
        par ^= 1;
    }

    // ---- epilogue: layer-2 for step 1023 (planes are in HP[w][par]) ----
    l2_step(&HP[w][par][0][0][0], fro, a2h, a2l, whh1v, b1v,
            h1r, c1r, l, out, bb, T_STEPS - 1);
}

extern "C" void kernel_launch(void* const* d_in, const int* in_sizes, int n_in,
                              void* d_out, int out_size, void* d_ws, size_t ws_size,
                              hipStream_t stream) {
    const float* input = (const float*)d_in[0];
    const float* W_ih0 = (const float*)d_in[1];
    const float* W_hh0 = (const float*)d_in[2];
    const float* b_ih0 = (const float*)d_in[3];
    const float* b_hh0 = (const float*)d_in[4];
    const float* W_ih1 = (const float*)d_in[5];
    const float* W_hh1 = (const float*)d_in[6];
    const float* b_ih1 = (const float*)d_in[7];
    const float* b_hh1 = (const float*)d_in[8];
    float* out = (float*)d_out;

    dim3 grid(BATCH / 8);   // 256 blocks -> 1 block/CU, 4 independent waves on 4 SIMDs
    dim3 block(256);
    lstm_v15_kernel<<<grid, block, 0, stream>>>(
        input, W_ih0, W_hh0, b_ih0, b_hh0, W_ih1, W_hh1, b_ih1, b_hh1, out);
}

// Round 8
// 532.581 us; speedup vs baseline: 1.8400x; 1.8400x over previous
//
#include <hip/hip_runtime.h>

#define T_STEPS 1024
#define BATCH 2048
#define BTILE 4
#define HS 36   // LDS row stride in u32 words; 36 % 32 == 4 -> conflict-free b128 reads

typedef short short8 __attribute__((ext_vector_type(8)));
typedef float f32x4 __attribute__((ext_vector_type(4)));
typedef float f32x2 __attribute__((ext_vector_type(2)));

__device__ __forceinline__ float fast_rcp(float x) {
#if __has_builtin(__builtin_amdgcn_rcpf)
    return __builtin_amdgcn_rcpf(x);
#else
    return 1.0f / x;
#endif
}

__device__ __forceinline__ float fast_exp2(float x) {
#if __has_builtin(__builtin_amdgcn_exp2f)
    return __builtin_amdgcn_exp2f(x);
#else
    return exp2f(x);
#endif
}

__device__ __forceinline__ float sigf(float x) {
    return fast_rcp(1.0f + fast_exp2(-1.44269504f * x));
}

// packed 2-lane sigmoid
__device__ __forceinline__ f32x2 sigf2(f32x2 v) {
    f32x2 t = v * (-1.44269504f);
    f32x2 e = {fast_exp2(t[0]), fast_exp2(t[1])};
    e = e + 1.0f;
    return f32x2{fast_rcp(e[0]), fast_rcp(e[1])};
}

__device__ __forceinline__ float tanh_fast(float x) {
    float e = fast_exp2(2.88539008f * x);
    return 1.0f - 2.0f * fast_rcp(e + 1.0f);
}

// float -> bf16 bits (round-to-nearest-even) — setup only
__device__ __forceinline__ unsigned f2bf(float x) {
    unsigned u = __float_as_uint(x);
    unsigned r = u + 0x7FFFu + ((u >> 16) & 1u);
    return r >> 16;
}
__device__ __forceinline__ float bf2f(unsigned b) {
    return __uint_as_float(b << 16);
}

// packed bf16 convert: dst = {hi16=bf16(b), lo16=bf16(a)}, RNE
__device__ __forceinline__ unsigned cvt_pk_bf16(float a, float b) {
    unsigned r;
    asm("v_cvt_pk_bf16_f32 %0, %1, %2" : "=v"(r) : "v"(a), "v"(b));
    return r;
}

// DPP conventions (HW-validated R2-R7): 0x110+N: lane l <- lane l-N (row-16);
// 0x100+N: lane l <- lane l+N. bank_mask: unselected banks keep OLD dst value.
__device__ __forceinline__ float sel4A(f32x4 a) {
    int v = __float_as_int(a[0]);                                        // bank 0 (r=0)
    v = __builtin_amdgcn_update_dpp(v, __float_as_int(a[1]), 0x114, 0xf, 0x2, false);
    v = __builtin_amdgcn_update_dpp(v, __float_as_int(a[2]), 0x118, 0xf, 0x4, false);
    v = __builtin_amdgcn_update_dpp(v, __float_as_int(a[3]), 0x11C, 0xf, 0x8, false);
    return __int_as_float(v);
}
__device__ __forceinline__ float dpp_shl4f(float v) {
    return __int_as_float(__builtin_amdgcn_update_dpp(0, __float_as_int(v), 0x104, 0xf, 0xf, true));
}

// v8 FINAL (session best: 530.8 µs harness / 583 µs rocprof).
// Structure: 4-wave barrier-exchange, BTILE=4, 2 de-phased blocks/CU.
// R1-R7 falsified every perturbation: barrier-drain relax (neutral),
// 2-chain ILP (-45%), L2 skew pipelines (-8/-9%), BTILE=8 (-23%),
// de-phase retune + setprio (-2%, unstable), barrier-free waves (-88%,
// MFMA issue ~17 cyc/inst/wave makes weight replication prohibitive).
// Step = 1366 cyc: ~700 VALU issue + ~370 matrix + ~300 exposed
// chain/skew. Problem shape (2048 batch / 256 CU / serial T) pins the
// partition; remaining idle is latency exposure, not a counter roofline.
__global__ __launch_bounds__(256, 2)
void lstm_v8_kernel(const float* __restrict__ input,
                    const float* __restrict__ W_ih0,
                    const float* __restrict__ W_hh0,
                    const float* __restrict__ b_ih0,
                    const float* __restrict__ b_hh0,
                    const float* __restrict__ W_ih1,
                    const float* __restrict__ W_hh1,
                    const float* __restrict__ b_ih1,
                    const float* __restrict__ b_hh1,
                    float* __restrict__ out)
{
    const int tid = threadIdx.x;
    const int w   = tid >> 6;
    const int l   = tid & 63;
    const int q16 = l >> 4;
    const int n16 = l & 15;
    const int nb  = l & 3;
    const int r   = (l >> 2) & 3;
    const int u   = 16 * w + 4 * q16 + r;
    const int bbase = blockIdx.x * BTILE;

    __shared__ __align__(16) unsigned Hbuf[2][3][16][HS];   // 13.8 KB
    __shared__ float Xb[2][BTILE][65];
    __shared__ float Lst[8];                                // h1[0..3], c1[4..7]

    for (int i = tid; i < 2 * 3 * 16 * HS; i += 256)
        reinterpret_cast<unsigned*>(Hbuf)[i] = 0u;
    if (tid < 8) Lst[tid] = 0.0f;

    // ---- L1 A-fragments: a1[g][kt] = W_hh0 tile (w+4g, kt) ----
    short8 a1[4][2];
    #pragma unroll
    for (int g = 0; g < 4; ++g) {
        #pragma unroll
        for (int kt = 0; kt < 2; ++kt) {
            const float* p = W_hh0 + (size_t)(16 * (w + 4 * g) + n16) * 64 + kt * 32 + q16 * 8;
            short8 a;
            #pragma unroll
            for (int j = 0; j < 8; ++j) a[j] = (short)f2bf(p[j]);
            a1[g][kt] = a;
        }
    }
    // ---- L2 A-fragments (hi/lo split), rows m>=4 zero ----
    short8 a2h[2], a2l[2];
    #pragma unroll
    for (int kt = 0; kt < 2; ++kt) {
        short8 ah = {0,0,0,0,0,0,0,0}, al = {0,0,0,0,0,0,0,0};
        if (n16 < 4) {
            const float* p = W_ih1 + (size_t)n16 * 64 + kt * 32 + q16 * 8;
            #pragma unroll
            for (int j = 0; j < 8; ++j) {
                unsigned hb = f2bf(p[j]);
                ah[j] = (short)hb;
                al[j] = (short)f2bf(p[j] - bf2f(hb));
            }
        }
        a2h[kt] = ah; a2l[kt] = al;
    }

    // activation constants for cell (nb, u), packed as float2 pairs
    f32x2 w01, w23, b01, b23;
    {
        float wgv[4], bgv[4];
        #pragma unroll
        for (int g = 0; g < 4; ++g) {
            int row = g * 64 + u;
            wgv[g] = W_ih0[row];
            bgv[g] = b_ih0[row] + b_hh0[row];
        }
        w01 = f32x2{wgv[0], wgv[1]}; w23 = f32x2{wgv[2], wgv[3]};
        b01 = f32x2{bgv[0], bgv[1]}; b23 = f32x2{bgv[2], bgv[3]};
    }
    float whh1v[4], b1v[4];
    #pragma unroll
    for (int g = 0; g < 4; ++g) { whh1v[g] = W_hh1[g]; b1v[g] = b_ih1[g] + b_hh1[g]; }

    const float* inrow = input + (size_t)(bbase + w) * T_STEPS;
    Xb[0][w][l] = inrow[l];
    float xnext = 0.0f;
    float c0 = 0.0f;

    __syncthreads();

    // ---- de-phase: second co-resident block sleeps ~320 cyc so the two
    // waves/SIMD cover each other's stalls instead of stalling in lockstep.
    // (R6: half-step sleep destabilized the equilibrium; 320 is the tuned
    // value from the original session — do not retune statically.)
    if (blockIdx.x & 256) {
        __builtin_amdgcn_s_sleep(5);
    }

    int par = 0;
    #pragma unroll 2
    for (int t = 0; t < T_STEPS; ++t) {
        if ((t & 63) == 0 && t + 64 < T_STEPS) xnext = inrow[t + 64 + l];
        const int cp = (t >> 6) & 1;

        // ---- B-fragments: h(t-1) ----
        const unsigned* Hrow = &Hbuf[par][0][n16][0];
        short8 hb0 = *reinterpret_cast<const short8*>(Hrow + 4 * q16);
        short8 hb1 = *reinterpret_cast<const short8*>(Hrow + 16 + 4 * q16);

        // ---- L1 MFMA ----
        f32x4 accv[4];
        #pragma unroll
        for (int g = 0; g < 4; ++g) {
            f32x4 z = {0.0f, 0.0f, 0.0f, 0.0f};
            z = __builtin_amdgcn_mfma_f32_16x16x32_bf16(a1[g][0], hb0, z, 0, 0, 0);
            z = __builtin_amdgcn_mfma_f32_16x16x32_bf16(a1[g][1], hb1, z, 0, 0, 0);
            accv[g] = z;
        }

        // ---- layer-2 for step t-1 (round-robin wave), in the MFMA shadow ----
        if (t > 0 && w == ((t - 1) & 3)) {
            const unsigned* Ch = &Hbuf[par][1][n16][0];
            const unsigned* Cl = &Hbuf[par][2][n16][0];
            short8 ch0 = *reinterpret_cast<const short8*>(Ch + 4 * q16);
            short8 ch1 = *reinterpret_cast<const short8*>(Ch + 16 + 4 * q16);
            short8 cl0 = *reinterpret_cast<const short8*>(Cl + 4 * q16);
            short8 cl1 = *reinterpret_cast<const short8*>(Cl + 16 + 4 * q16);
            float h1p = Lst[nb], c1p = Lst[4 + nb];
            f32x4 zA = {0.0f, 0.0f, 0.0f, 0.0f};
            f32x4 zB = {0.0f, 0.0f, 0.0f, 0.0f};
            zA = __builtin_amdgcn_mfma_f32_16x16x32_bf16(a2h[0], ch0, zA, 0, 0, 0);
            zB = __builtin_amdgcn_mfma_f32_16x16x32_bf16(a2l[1], ch1, zB, 0, 0, 0);
            zA = __builtin_amdgcn_mfma_f32_16x16x32_bf16(a2h[1], ch1, zA, 0, 0, 0);
            zB = __builtin_amdgcn_mfma_f32_16x16x32_bf16(a2h[0], cl0, zB, 0, 0, 0);
            zA = __builtin_amdgcn_mfma_f32_16x16x32_bf16(a2l[0], ch0, zA, 0, 0, 0);
            zB = __builtin_amdgcn_mfma_f32_16x16x32_bf16(a2h[1], cl1, zB, 0, 0, 0);
            f32x4 z = zA + zB;
            float g1i = z[0] + b1v[0] + h1p * whh1v[0];
            float g1f = z[1] + b1v[1] + h1p * whh1v[1];
            float g1g = z[2] + b1v[2] + h1p * whh1v[2];
            float g1o = z[3] + b1v[3] + h1p * whh1v[3];
            float c1n = sigf(g1f) * c1p + sigf(g1i) * tanh_fast(g1g);
            float h1n = sigf(g1o) * tanh_fast(c1n);
            if (l < 4) {
                out[(size_t)(bbase + l) * T_STEPS + (t - 1)] = c1n;
                Lst[l] = h1n;
                Lst[4 + l] = c1n;
            }
        }

        // ---- in-register gate redistribution (bank-masked DPP, 12 inst) ----
        float g4[4];
        #pragma unroll
        for (int g = 0; g < 4; ++g) g4[g] = sel4A(accv[g]);

        // ---- layer-1 activation for cell (nb, u), packed math ----
        float x = Xb[cp][nb][t & 63];
        f32x2 xx = {x, x};
        f32x2 gif = f32x2{g4[0], g4[1]} + (xx * w01 + b01);   // (i, f)
        f32x2 ggo = f32x2{g4[2], g4[3]} + (xx * w23 + b23);   // (g, o)

        f32x2 sif = sigf2(gif);                  // sig(i), sig(f)
        float tg  = tanh_fast(ggo[0]);
        float c0n = sif[1] * c0 + sif[0] * tg;
        c0 = c0n;
        float h0n = sigf(ggo[1]) * tanh_fast(c0n);

        // ---- pack h / c0hi / c0lo pairs via v_cvt_pk_bf16_f32 ----
        float ph = dpp_shl4f(h0n);               // partner unit u+1 (lane l+4)
        float pc = dpp_shl4f(c0n);
        unsigned hword  = cvt_pk_bf16(h0n, ph);  // lo=own, hi=partner
        unsigned chword = cvt_pk_bf16(c0n, pc);
        float hi_own = bf2f(chword & 0xFFFFu);   // own bf16(c0n) as f32
        float lo_own = c0n - hi_own;
        float plo = dpp_shl4f(lo_own);
        unsigned clword = cvt_pk_bf16(lo_own, plo);
        if (!(l & 4)) {                          // r even: owns pair (u, u+1)
            int widx = 8 * w + 2 * q16 + (r >> 1);
            Hbuf[par ^ 1][0][nb][widx] = hword;
            Hbuf[par ^ 1][1][nb][widx] = chword;
            Hbuf[par ^ 1][2][nb][widx] = clword;
        }
        if ((t & 63) == 63 && t + 1 < T_STEPS) Xb[cp ^ 1][w][l] = xnext;

        __syncthreads();
        par ^= 1;
    }

    // ---- epilogue: layer-2 for step 1023 (wave 3) ----
    if (w == 3) {
        const unsigned* Ch = &Hbuf[par][1][n16][0];
        const unsigned* Cl = &Hbuf[par][2][n16][0];
        short8 ch0 = *reinterpret_cast<const short8*>(Ch + 4 * q16);
        short8 ch1 = *reinterpret_cast<const short8*>(Ch + 16 + 4 * q16);
        short8 cl0 = *reinterpret_cast<const short8*>(Cl + 4 * q16);
        short8 cl1 = *reinterpret_cast<const short8*>(Cl + 16 + 4 * q16);
        float h1p = Lst[nb], c1p = Lst[4 + nb];
        f32x4 zA = {0.0f, 0.0f, 0.0f, 0.0f};
        f32x4 zB = {0.0f, 0.0f, 0.0f, 0.0f};
        zA = __builtin_amdgcn_mfma_f32_16x16x32_bf16(a2h[0], ch0, zA, 0, 0, 0);
        zB = __builtin_amdgcn_mfma_f32_16x16x32_bf16(a2l[1], ch1, zB, 0, 0, 0);
        zA = __builtin_amdgcn_mfma_f32_16x16x32_bf16(a2h[1], ch1, zA, 0, 0, 0);
        zB = __builtin_amdgcn_mfma_f32_16x16x32_bf16(a2h[0], cl0, zB, 0, 0, 0);
        zA = __builtin_amdgcn_mfma_f32_16x16x32_bf16(a2l[0], ch0, zA, 0, 0, 0);
        zB = __builtin_amdgcn_mfma_f32_16x16x32_bf16(a2h[1], cl1, zB, 0, 0, 0);
        f32x4 z = zA + zB;
        float g1i = z[0] + b1v[0] + h1p * whh1v[0];
        float g1f = z[1] + b1v[1] + h1p * whh1v[1];
        float g1g = z[2] + b1v[2] + h1p * whh1v[2];
        float g1o = z[3] + b1v[3] + h1p * whh1v[3];
        float c1n = sigf(g1f) * c1p + sigf(g1i) * tanh_fast(g1g);
        if (l < 4)
            out[(size_t)(bbase + l) * T_STEPS + (T_STEPS - 1)] = c1n;
    }
}

extern "C" void kernel_launch(void* const* d_in, const int* in_sizes, int n_in,
                              void* d_out, int out_size, void* d_ws, size_t ws_size,
                              hipStream_t stream) {
    const float* input = (const float*)d_in[0];
    const float* W_ih0 = (const float*)d_in[1];
    const float* W_hh0 = (const float*)d_in[2];
    const float* b_ih0 = (const float*)d_in[3];
    const float* b_hh0 = (const float*)d_in[4];
    const float* W_ih1 = (const float*)d_in[5];
    const float* W_hh1 = (const float*)d_in[6];
    const float* b_ih1 = (const float*)d_in[7];
    const float* b_hh1 = (const float*)d_in[8];
    float* out = (float*)d_out;

    dim3 grid(BATCH / BTILE);   // 512 blocks -> 2 blocks/CU, 2 waves/SIMD
    dim3 block(256);
    lstm_v8_kernel<<<grid, block, 0, stream>>>(
        input, W_ih0, W_hh0, b_ih0, b_hh0, W_ih1, W_hh1, b_ih1, b_hh1, out);
}